// Round 9
// baseline (599.410 us; speedup 1.0000x reference)
//
#include <hip/hip_runtime.h>
#include <hip/hip_bf16.h>

#define D_MODEL 1024
#define D_STATE 16
#define D_CONV  4
#define D_INNER 2048
#define BATCH   2
#define SEQ     2048
#define NTOK    (BATCH * SEQ)      // 4096
#define NXZ     (2 * D_INNER)      // 4096
#define NDBL    (2 * D_STATE + 1)  // 33
#define XROW    40                 // padded x_dbl row: [dt,_,_,_, B0..15, C0..15, pad4]
#define CHUNK   32
#define NCHUNK  (SEQ / CHUNK)      // 64
#define XT      4                  // tokens per xdbl block

typedef __attribute__((ext_vector_type(8))) short bf16x8;
typedef __attribute__((ext_vector_type(4))) float f32x4;

__device__ __forceinline__ float silu_fast(float x) {
    return x / (1.0f + __expf(-x));
}
__device__ __forceinline__ float softplus_fast(float x) {
    float r = __logf(1.0f + __expf(x));
    return (x > 20.f) ? x : r;
}
__device__ __forceinline__ short f2bf(float f) {
    __hip_bfloat16 h = __float2bfloat16(f);
    return __builtin_bit_cast(short, h);
}
__device__ __forceinline__ float bf2f(short s) {
    return __bfloat162float(__builtin_bit_cast(__hip_bfloat16, s));
}
__device__ __forceinline__ void gload_lds16(const void* g, void* l) {
    __builtin_amdgcn_global_load_lds(
        (const __attribute__((address_space(1))) void*)g,
        (__attribute__((address_space(3))) void*)l, 16, 0, 0);
}

// ---------------------------------------------------------------------------
// Split fp32 -> (hi, lo) bf16 pair.  n4 = count/4.
// ---------------------------------------------------------------------------
__global__ void split_kernel(const float* __restrict__ in, short* __restrict__ hi,
                             short* __restrict__ lo, int n4)
{
    int i = blockIdx.x * blockDim.x + threadIdx.x;
    if (i >= n4) return;
    float4 v = ((const float4*)in)[i];
    short4 h, l;
    h.x = f2bf(v.x); l.x = f2bf(v.x - bf2f(h.x));
    h.y = f2bf(v.y); l.y = f2bf(v.y - bf2f(h.y));
    h.z = f2bf(v.z); l.z = f2bf(v.z - bf2f(h.z));
    h.w = f2bf(v.w); l.w = f2bf(v.w - bf2f(h.w));
    ((short4*)hi)[i] = h;
    ((short4*)lo)[i] = l;
}

// ---------------------------------------------------------------------------
// Split-bf16 MFMA GEMM, double-buffered LDS, split-K via blockIdx.z.
// C_part[z] = A[:, z*kLen : (z+1)*kLen] * B[:, same]^T  (full K = row stride).
// 128x128 tile, BK=32, 4 waves; ONE barrier per K-step; stage of step s+1
// issued right after the barrier so 48 MFMAs hide its HBM latency.
// XCD-aware bijective block swizzle (grid %8 == 0 in all launches).
// ---------------------------------------------------------------------------
__launch_bounds__(256, 2)
__global__ void mfma_gemm_split(const short* __restrict__ Ahi, const short* __restrict__ Alo,
                                const short* __restrict__ Bhi, const short* __restrict__ Blo,
                                float* __restrict__ C, int M, int N, int K,
                                int kLen, size_t partStride)
{
    __shared__ short sAh[2][4096], sAl[2][4096], sBh[2][4096], sBl[2][4096];
    const int tid  = threadIdx.x;
    const int lane = tid & 63;
    const int wave = tid >> 6;
    const int wm = wave >> 1, wn = wave & 1;

    // XCD swizzle: hw flat id -> contiguous tile chunk per XCD (bijective, nwg%8==0)
    const int gx = gridDim.x, gy = gridDim.y;
    const int nwg = gx * gy * gridDim.z;
    int f = (blockIdx.z * gy + blockIdx.y) * gx + blockIdx.x;
    f = (f & 7) * (nwg >> 3) + (f >> 3);
    const int bz  = f / (gx * gy);
    const int rem = f % (gx * gy);
    const int bm = rem / gx;
    const int bn = rem % gx;

    const int kBeg = bz * kLen;
    float* Cp = C + (size_t)bz * partStride;

    const int r0a = bm * 128, r0b = bn * 128;

    auto stage = [&](int k0, int buf) {
#pragma unroll
        for (int i = 0; i < 2; ++i) {
            const int off = i * 4096 + tid * 16;   // byte offset within one buffer
            const int g   = off >> 11;             // granule 0..3
            const int row = (off >> 4) & 127;      // tile row 0..127
            const size_t ea = (size_t)(r0a + row) * K + k0 + g * 8;
            const size_t eb = (size_t)(r0b + row) * K + k0 + g * 8;
            const int dst = buf * 8192 + i * 4096 + wave * 1024;  // wave-uniform
            gload_lds16(Ahi + ea, (char*)sAh + dst);
            gload_lds16(Alo + ea, (char*)sAl + dst);
            gload_lds16(Bhi + eb, (char*)sBh + dst);
            gload_lds16(Blo + eb, (char*)sBl + dst);
        }
    };

    f32x4 acc[4][4] = {};
    const int nsteps = kLen / 32;

    stage(kBeg, 0);
    for (int s = 0; s < nsteps; ++s) {
        __syncthreads();   // buf[s&1] staged (vmcnt) + prev readers done (lgkm)
        if (s + 1 < nsteps) stage(kBeg + (s + 1) * 32, (s + 1) & 1);

        const int buf = s & 1;
        const int g = lane >> 4;
        const bf16x8* pAh = (const bf16x8*)sAh + buf * 512 + g * 128;
        const bf16x8* pAl = (const bf16x8*)sAl + buf * 512 + g * 128;
        const bf16x8* pBh = (const bf16x8*)sBh + buf * 512 + g * 128;
        const bf16x8* pBl = (const bf16x8*)sBl + buf * 512 + g * 128;

        bf16x8 ah[4], al[4], bh[4], bl[4];
#pragma unroll
        for (int m = 0; m < 4; ++m) {
            const int rowA = wm * 64 + m * 16 + (lane & 15);
            const int rowB = wn * 64 + m * 16 + (lane & 15);
            ah[m] = pAh[rowA];
            al[m] = pAl[rowA];
            bh[m] = pBh[rowB];
            bl[m] = pBl[rowB];
        }
#pragma unroll
        for (int m = 0; m < 4; ++m)
#pragma unroll
            for (int n = 0; n < 4; ++n) {
                acc[m][n] = __builtin_amdgcn_mfma_f32_16x16x32_bf16(ah[m], bh[n], acc[m][n], 0, 0, 0);
                acc[m][n] = __builtin_amdgcn_mfma_f32_16x16x32_bf16(ah[m], bl[n], acc[m][n], 0, 0, 0);
                acc[m][n] = __builtin_amdgcn_mfma_f32_16x16x32_bf16(al[m], bh[n], acc[m][n], 0, 0, 0);
            }
    }

    // epilogue: C/D layout col=lane&15, row=(lane>>4)*4+reg
#pragma unroll
    for (int m = 0; m < 4; ++m) {
        const int row = bm * 128 + wm * 64 + m * 16 + ((lane >> 4) << 2);
#pragma unroll
        for (int n = 0; n < 4; ++n) {
            const int col = bn * 128 + wn * 64 + n * 16 + (lane & 15);
#pragma unroll
            for (int r = 0; r < 4; ++r)
                Cp[(size_t)(row + r) * N + col] = acc[m][n][r];
        }
    }
}

// ---------------------------------------------------------------------------
// o = a + b (float4 granularity) — split-K reduction epilogue.
// ---------------------------------------------------------------------------
__global__ void add2_kernel(const float* __restrict__ a, const float* __restrict__ b,
                            float* __restrict__ o, int n4)
{
    int i = blockIdx.x * blockDim.x + threadIdx.x;
    if (i >= n4) return;
    float4 va = ((const float4*)a)[i];
    float4 vb = ((const float4*)b)[i];
    ((float4*)o)[i] = make_float4(va.x + vb.x, va.y + vb.y, va.z + vb.z, va.w + vb.w);
}

// ---------------------------------------------------------------------------
// Depthwise causal conv (k=4) + bias + SiLU (fast).
// ---------------------------------------------------------------------------
__global__ void conv_silu_kernel(const float* __restrict__ xz,
                                 const float* __restrict__ conv_w,
                                 const float* __restrict__ conv_b,
                                 float* __restrict__ xi)
{
    int idx = blockIdx.x * blockDim.x + threadIdx.x;
    if (idx >= NTOK * D_INNER) return;
    int d = idx % D_INNER;
    int t = idx / D_INNER;
    int l = t % SEQ;
    int b = t / SEQ;

    float w0 = conv_w[d * 4 + 0], w1 = conv_w[d * 4 + 1];
    float w2 = conv_w[d * 4 + 2], w3 = conv_w[d * 4 + 3];

    const float* base = xz + ((size_t)b * SEQ) * NXZ + d;
    float acc = conv_b[d];
    if (l >= 3) acc = fmaf(w0, base[(size_t)(l - 3) * NXZ], acc);
    if (l >= 2) acc = fmaf(w1, base[(size_t)(l - 2) * NXZ], acc);
    if (l >= 1) acc = fmaf(w2, base[(size_t)(l - 1) * NXZ], acc);
    acc = fmaf(w3, base[(size_t)l * NXZ], acc);
    xi[idx] = silu_fast(acc);
}

// ---------------------------------------------------------------------------
// x_dbl: XT tokens per block; one W_x read feeds XT FMA streams.
// Padded row layout: slot 0 = dt_raw, 4..19 = B, 20..35 = C.
// ---------------------------------------------------------------------------
__launch_bounds__(256)
__global__ void xdbl_kernel(const float* __restrict__ xi,
                            const float* __restrict__ W_x,
                            float* __restrict__ xdbl)
{
    __shared__ float rows[XT][D_INNER];
    const int t0 = blockIdx.x * XT;
    for (int i = threadIdx.x; i < XT * D_INNER; i += 256)
        rows[i >> 11][i & 2047] = xi[(size_t)(t0 + (i >> 11)) * D_INNER + (i & 2047)];
    __syncthreads();

    const int wave = threadIdx.x >> 6;
    const int lane = threadIdx.x & 63;
    for (int e = wave; e < NDBL; e += 4) {
        const float* wr = W_x + (size_t)e * D_INNER;
        float s0 = 0.f, s1 = 0.f, s2 = 0.f, s3 = 0.f;
        for (int i = lane; i < D_INNER; i += 64) {
            float w = wr[i];
            s0 = fmaf(rows[0][i], w, s0);
            s1 = fmaf(rows[1][i], w, s1);
            s2 = fmaf(rows[2][i], w, s2);
            s3 = fmaf(rows[3][i], w, s3);
        }
#pragma unroll
        for (int off = 32; off; off >>= 1) {
            s0 += __shfl_xor(s0, off);
            s1 += __shfl_xor(s1, off);
            s2 += __shfl_xor(s2, off);
            s3 += __shfl_xor(s3, off);
        }
        if (lane == 0) {
            const int slot = (e == 0 ? 0 : e + 3);
            xdbl[(size_t)(t0 + 0) * XROW + slot] = s0;
            xdbl[(size_t)(t0 + 1) * XROW + slot] = s1;
            xdbl[(size_t)(t0 + 2) * XROW + slot] = s2;
            xdbl[(size_t)(t0 + 3) * XROW + slot] = s3;
        }
    }
}

// ---------------------------------------------------------------------------
// Chunked scan pass 1: thread per (b, d, chunk); all 16 n-states in registers.
// ---------------------------------------------------------------------------
__launch_bounds__(256)
__global__ void scan_pass1(const float* __restrict__ xdbl,
                           const float* __restrict__ xi,
                           const float* __restrict__ W_dt,
                           const float* __restrict__ b_dt,
                           const float* __restrict__ A_log,
                           float* __restrict__ aprod,
                           float* __restrict__ hloc)
{
    const int d = blockIdx.x * 256 + threadIdx.x;
    const int c = blockIdx.y;
    const int b = blockIdx.z;

    float A[16];
    {
        const float4* ar = (const float4*)(A_log + (size_t)d * 16);
#pragma unroll
        for (int q = 0; q < 4; ++q) {
            float4 v = ar[q];
            A[q * 4 + 0] = -__expf(v.x);
            A[q * 4 + 1] = -__expf(v.y);
            A[q * 4 + 2] = -__expf(v.z);
            A[q * 4 + 3] = -__expf(v.w);
        }
    }
    const float wdt = W_dt[d], bdt = b_dt[d];

    const float* xd = xdbl + ((size_t)b * SEQ + c * CHUNK) * XROW;
    const float* xp = xi + ((size_t)b * SEQ + c * CHUNK) * D_INNER + d;

    float h[16], ap[16], Bv[16];
#pragma unroll
    for (int n = 0; n < 16; ++n) { h[n] = 0.f; ap[n] = 1.f; }

    for (int l = 0; l < CHUNK; ++l) {
        float raw = xd[0];
#pragma unroll
        for (int q = 0; q < 4; ++q) {
            float4 v = *(const float4*)(xd + 4 + q * 4);
            Bv[q * 4 + 0] = v.x; Bv[q * 4 + 1] = v.y;
            Bv[q * 4 + 2] = v.z; Bv[q * 4 + 3] = v.w;
        }
        float xv = xp[0];
        float dtv = softplus_fast(fmaf(raw, wdt, bdt));
        float dtx = dtv * xv;
#pragma unroll
        for (int n = 0; n < 16; ++n) {
            float e = __expf(dtv * A[n]);
            h[n]  = fmaf(e, h[n], Bv[n] * dtx);
            ap[n] *= e;
        }
        xd += XROW; xp += D_INNER;
    }

    size_t s = (((size_t)b * NCHUNK + c) * D_INNER + d) * 16;
#pragma unroll
    for (int q = 0; q < 4; ++q) {
        *(float4*)(aprod + s + q * 4) = make_float4(ap[q*4], ap[q*4+1], ap[q*4+2], ap[q*4+3]);
        *(float4*)(hloc  + s + q * 4) = make_float4(h[q*4],  h[q*4+1],  h[q*4+2],  h[q*4+3]);
    }
}

// ---------------------------------------------------------------------------
// Chunked scan combine: serial over NCHUNK summaries; h_start in-place.
// ---------------------------------------------------------------------------
__global__ void scan_combine(float* __restrict__ aprod,
                             const float* __restrict__ hloc)
{
    int idx = blockIdx.x * blockDim.x + threadIdx.x;  // b*32768 + d*16 + n
    int b  = idx >> 15;
    int dn = idx & 32767;
    float hs = 0.f;
#pragma unroll
    for (int c = 0; c < NCHUNK; ++c) {
        size_t s = (((size_t)b * NCHUNK + c) << 15) + dn;
        float ap = aprod[s];
        float hl = hloc[s];
        aprod[s] = hs;                 // h_start for this chunk
        hs = fmaf(ap, hs, hl);
    }
}

// ---------------------------------------------------------------------------
// Chunked scan pass 2: rescan from h_start; emit gated y in-place into xi.
// ---------------------------------------------------------------------------
__launch_bounds__(256)
__global__ void scan_pass2(const float* __restrict__ xdbl,
                           float* __restrict__ xi,
                           const float* __restrict__ xz,
                           const float* __restrict__ W_dt,
                           const float* __restrict__ b_dt,
                           const float* __restrict__ A_log,
                           const float* __restrict__ Dvec,
                           const float* __restrict__ hstart)
{
    const int d = blockIdx.x * 256 + threadIdx.x;
    const int c = blockIdx.y;
    const int b = blockIdx.z;

    float A[16];
    {
        const float4* ar = (const float4*)(A_log + (size_t)d * 16);
#pragma unroll
        for (int q = 0; q < 4; ++q) {
            float4 v = ar[q];
            A[q * 4 + 0] = -__expf(v.x);
            A[q * 4 + 1] = -__expf(v.y);
            A[q * 4 + 2] = -__expf(v.z);
            A[q * 4 + 3] = -__expf(v.w);
        }
    }
    const float wdt = W_dt[d], bdt = b_dt[d], Dd = Dvec[d];

    const float* xd = xdbl + ((size_t)b * SEQ + c * CHUNK) * XROW;
    float*       xp = xi + ((size_t)b * SEQ + c * CHUNK) * D_INNER + d;
    const float* zp = xz + ((size_t)b * SEQ + c * CHUNK) * NXZ + D_INNER + d;

    float h[16], Bv[16], Cv[16];
    {
        size_t s = (((size_t)b * NCHUNK + c) * D_INNER + d) * 16;
#pragma unroll
        for (int q = 0; q < 4; ++q) {
            float4 v = *(const float4*)(hstart + s + q * 4);
            h[q * 4 + 0] = v.x; h[q * 4 + 1] = v.y;
            h[q * 4 + 2] = v.z; h[q * 4 + 3] = v.w;
        }
    }

    for (int l = 0; l < CHUNK; ++l) {
        float raw = xd[0];
#pragma unroll
        for (int q = 0; q < 4; ++q) {
            float4 v = *(const float4*)(xd + 4 + q * 4);
            Bv[q * 4 + 0] = v.x; Bv[q * 4 + 1] = v.y;
            Bv[q * 4 + 2] = v.z; Bv[q * 4 + 3] = v.w;
            float4 w = *(const float4*)(xd + 20 + q * 4);
            Cv[q * 4 + 0] = w.x; Cv[q * 4 + 1] = w.y;
            Cv[q * 4 + 2] = w.z; Cv[q * 4 + 3] = w.w;
        }
        float xv = xp[0];
        float zv = zp[0];
        float dtv = softplus_fast(fmaf(raw, wdt, bdt));
        float dtx = dtv * xv;

        float p0 = 0.f, p1 = 0.f, p2 = 0.f, p3 = 0.f;
#pragma unroll
        for (int q = 0; q < 4; ++q) {
            float e0 = __expf(dtv * A[q*4+0]);
            float e1 = __expf(dtv * A[q*4+1]);
            float e2 = __expf(dtv * A[q*4+2]);
            float e3 = __expf(dtv * A[q*4+3]);
            h[q*4+0] = fmaf(e0, h[q*4+0], Bv[q*4+0] * dtx);
            h[q*4+1] = fmaf(e1, h[q*4+1], Bv[q*4+1] * dtx);
            h[q*4+2] = fmaf(e2, h[q*4+2], Bv[q*4+2] * dtx);
            h[q*4+3] = fmaf(e3, h[q*4+3], Bv[q*4+3] * dtx);
            p0 = fmaf(h[q*4+0], Cv[q*4+0], p0);
            p1 = fmaf(h[q*4+1], Cv[q*4+1], p1);
            p2 = fmaf(h[q*4+2], Cv[q*4+2], p2);
            p3 = fmaf(h[q*4+3], Cv[q*4+3], p3);
        }
        float y = (p0 + p1) + (p2 + p3) + Dd * xv;
        xp[0] = y * silu_fast(zv);

        xd += XROW; xp += D_INNER; zp += NXZ;
    }
}

// ---------------------------------------------------------------------------
extern "C" void kernel_launch(void* const* d_in, const int* in_sizes, int n_in,
                              void* d_out, int out_size, void* d_ws, size_t ws_size,
                              hipStream_t stream)
{
    (void)in_sizes; (void)n_in; (void)out_size; (void)ws_size;

    const float* x      = (const float*)d_in[0];
    const float* W_in   = (const float*)d_in[1];
    const float* conv_w = (const float*)d_in[2];
    const float* conv_b = (const float*)d_in[3];
    const float* W_x    = (const float*)d_in[4];
    const float* W_dt   = (const float*)d_in[5];
    const float* b_dt   = (const float*)d_in[6];
    const float* A_log  = (const float*)d_in[7];
    const float* Dvec   = (const float*)d_in[8];
    const float* W_out  = (const float*)d_in[9];
    float* out = (float*)d_out;

    // ---- workspace map ----
    float* xz   = (float*)d_ws;                    // 4096x4096 f32 (64MB)
    float* xi   = xz + (size_t)NTOK * NXZ;         // 4096x2048 f32 (33.5MB)
    float* xdbl = xi + (size_t)NTOK * D_INNER;     // 4096x40 f32 (padded)
    float* R    = xdbl + (size_t)NTOK * XROW;      // shared region

    // phase-1 occupants of R: hi/lo splits of x and W_in (33.5MB)
    short* x_hi   = (short*)R;
    short* x_lo   = x_hi + (size_t)NTOK * D_MODEL;
    short* Win_hi = x_lo + (size_t)NTOK * D_MODEL;
    short* Win_lo = Win_hi + (size_t)NXZ * D_MODEL;
    // phase-2 occupants of R: scan buffers (aprod doubles as hstart; 33.5MB)
    float* aprod  = R;
    float* hloc   = aprod + (size_t)BATCH * NCHUNK * D_INNER * 16;
    // phase-3 occupants of xz region (z consumed by pass2): y / W_out splits
    short* y_hi   = (short*)xz;
    short* y_lo   = y_hi + (size_t)NTOK * D_INNER;
    short* Wou_hi = y_lo + (size_t)NTOK * D_INNER;
    short* Wou_lo = Wou_hi + (size_t)D_MODEL * D_INNER;
    // phase-3 occupants of xi region (xi dead after y split): split-K partials
    float* part0  = xi;                            // 4096x1024
    float* part1  = part0 + (size_t)NTOK * D_MODEL;

    // 0) split x and W_in to bf16 hi/lo
    split_kernel<<<(NTOK * D_MODEL / 4 + 255) / 256, 256, 0, stream>>>(x, x_hi, x_lo, NTOK * D_MODEL / 4);
    split_kernel<<<(NXZ * D_MODEL / 4 + 255) / 256, 256, 0, stream>>>(W_in, Win_hi, Win_lo, NXZ * D_MODEL / 4);

    // 1) xz = x @ W_in^T   (M=4096, N=4096, K=1024; single K-slab)
    {
        dim3 grid(NXZ / 128, NTOK / 128, 1);   // 1024 blocks
        mfma_gemm_split<<<grid, 256, 0, stream>>>(x_hi, x_lo, Win_hi, Win_lo, xz,
                                                  NTOK, NXZ, D_MODEL, D_MODEL, 0);
    }
    // 2) depthwise conv + SiLU -> xi
    {
        int total = NTOK * D_INNER;
        conv_silu_kernel<<<(total + 255) / 256, 256, 0, stream>>>(xz, conv_w, conv_b, xi);
    }
    // 3) x_dbl = xi @ W_x^T  (padded rows)
    xdbl_kernel<<<NTOK / XT, 256, 0, stream>>>(xi, W_x, xdbl);

    // 4) chunked selective scan (register-resident n-states)
    {
        dim3 grid(D_INNER / 256, NCHUNK, BATCH);
        scan_pass1<<<grid, 256, 0, stream>>>(xdbl, xi, W_dt, b_dt, A_log, aprod, hloc);
        scan_combine<<<(BATCH * D_INNER * 16) / 256, 256, 0, stream>>>(aprod, hloc);
        scan_pass2<<<grid, 256, 0, stream>>>(xdbl, xi, xz, W_dt, b_dt, A_log, Dvec, aprod);
    }
    // 5) split y (=xi) and W_out; out = y @ W_out^T via split-K=2 + add
    split_kernel<<<(NTOK * D_INNER / 4 + 255) / 256, 256, 0, stream>>>(xi, y_hi, y_lo, NTOK * D_INNER / 4);
    split_kernel<<<(D_MODEL * D_INNER / 4 + 255) / 256, 256, 0, stream>>>(W_out, Wou_hi, Wou_lo, D_MODEL * D_INNER / 4);
    {
        dim3 grid(D_MODEL / 128, NTOK / 128, 2);   // 512 blocks (2 k-halves)
        mfma_gemm_split<<<grid, 256, 0, stream>>>(y_hi, y_lo, Wou_hi, Wou_lo, part0,
                                                  NTOK, D_MODEL, D_INNER, D_INNER / 2,
                                                  (size_t)NTOK * D_MODEL);
        add2_kernel<<<(NTOK * D_MODEL / 4 + 255) / 256, 256, 0, stream>>>(part0, part1, out, NTOK * D_MODEL / 4);
    }
}

// Round 10
// 591.054 us; speedup vs baseline: 1.0141x; 1.0141x over previous
//
#include <hip/hip_runtime.h>
#include <hip/hip_bf16.h>

#define D_MODEL 1024
#define D_STATE 16
#define D_CONV  4
#define D_INNER 2048
#define BATCH   2
#define SEQ     2048
#define NTOK    (BATCH * SEQ)      // 4096
#define NXZ     (2 * D_INNER)      // 4096
#define NDBL    (2 * D_STATE + 1)  // 33
#define XROW    40                 // padded x_dbl row: [dt,_,_,_, B0..15, C0..15, pad4]
#define CHUNK   32
#define NCHUNK  (SEQ / CHUNK)      // 64
#define XT      4                  // tokens per xdbl block

typedef __attribute__((ext_vector_type(8))) short bf16x8;
typedef __attribute__((ext_vector_type(4))) float f32x4;

__device__ __forceinline__ float silu_fast(float x) {
    return x / (1.0f + __expf(-x));
}
__device__ __forceinline__ float softplus_fast(float x) {
    float r = __logf(1.0f + __expf(x));
    return (x > 20.f) ? x : r;
}
__device__ __forceinline__ short f2bf(float f) {
    __hip_bfloat16 h = __float2bfloat16(f);
    return __builtin_bit_cast(short, h);
}
__device__ __forceinline__ float bf2f(short s) {
    return __bfloat162float(__builtin_bit_cast(__hip_bfloat16, s));
}
__device__ __forceinline__ void gload_lds16(const void* g, void* l) {
    __builtin_amdgcn_global_load_lds(
        (const __attribute__((address_space(1))) void*)g,
        (__attribute__((address_space(3))) void*)l, 16, 0, 0);
}

// ---------------------------------------------------------------------------
// Split fp32 -> (hi, lo) bf16 pair.  n4 = count/4.
// ---------------------------------------------------------------------------
__global__ void split_kernel(const float* __restrict__ in, short* __restrict__ hi,
                             short* __restrict__ lo, int n4)
{
    int i = blockIdx.x * blockDim.x + threadIdx.x;
    if (i >= n4) return;
    float4 v = ((const float4*)in)[i];
    short4 h, l;
    h.x = f2bf(v.x); l.x = f2bf(v.x - bf2f(h.x));
    h.y = f2bf(v.y); l.y = f2bf(v.y - bf2f(h.y));
    h.z = f2bf(v.z); l.z = f2bf(v.z - bf2f(h.z));
    h.w = f2bf(v.w); l.w = f2bf(v.w - bf2f(h.w));
    ((short4*)hi)[i] = h;
    ((short4*)lo)[i] = l;
}

// ---------------------------------------------------------------------------
// Split-bf16 MFMA GEMM (round-8 structure: single 32KB buffer, two barriers
// per K-step, stage of k+1 issued after frag reads so 48 MFMAs hide it).
// Split-K via blockIdx.z: C_part[z] = A[:, z*kLen:(z+1)*kLen] * B[...]^T.
// NO XCD swizzle (measured: swizzle doubled FETCH_SIZE, 96->215MB).
// ---------------------------------------------------------------------------
__launch_bounds__(256, 3)
__global__ void mfma_gemm_split(const short* __restrict__ Ahi, const short* __restrict__ Alo,
                                const short* __restrict__ Bhi, const short* __restrict__ Blo,
                                float* __restrict__ C, int M, int N, int K,
                                int kLen, size_t partStride)
{
    __shared__ short sAh[4096], sAl[4096], sBh[4096], sBl[4096];
    const int tid  = threadIdx.x;
    const int lane = tid & 63;
    const int wave = tid >> 6;
    const int bm = blockIdx.y, bn = blockIdx.x, bz = blockIdx.z;
    const int wm = wave >> 1, wn = wave & 1;

    const int kBeg = bz * kLen;
    float* Cp = C + (size_t)bz * partStride;

    const int r0a = bm * 128, r0b = bn * 128;

    auto stage = [&](int k0) {
#pragma unroll
        for (int i = 0; i < 2; ++i) {
            const int off = i * 4096 + tid * 16;   // LDS byte offset this lane fills
            const int g   = off >> 11;             // granule 0..3
            const int row = (off >> 4) & 127;      // tile row 0..127
            const size_t ea = (size_t)(r0a + row) * K + k0 + g * 8;
            const size_t eb = (size_t)(r0b + row) * K + k0 + g * 8;
            gload_lds16(Ahi + ea, (char*)sAh + i * 4096 + wave * 1024);
            gload_lds16(Alo + ea, (char*)sAl + i * 4096 + wave * 1024);
            gload_lds16(Bhi + eb, (char*)sBh + i * 4096 + wave * 1024);
            gload_lds16(Blo + eb, (char*)sBl + i * 4096 + wave * 1024);
        }
    };

    f32x4 acc[4][4] = {};
    const int kEnd = kBeg + kLen;

    stage(kBeg);
    for (int k0 = kBeg; k0 < kEnd; k0 += 32) {
        __syncthreads();   // staged data for k0 visible (drains vmcnt)

        const int g = lane >> 4;
        bf16x8 ah[4], al[4], bh[4], bl[4];
#pragma unroll
        for (int m = 0; m < 4; ++m) {
            const int rowA = wm * 64 + m * 16 + (lane & 15);
            const int rowB = wn * 64 + m * 16 + (lane & 15);
            ah[m] = ((const bf16x8*)sAh)[g * 128 + rowA];
            al[m] = ((const bf16x8*)sAl)[g * 128 + rowA];
            bh[m] = ((const bf16x8*)sBh)[g * 128 + rowB];
            bl[m] = ((const bf16x8*)sBl)[g * 128 + rowB];
        }
        __syncthreads();   // frags in regs (lgkmcnt drained); LDS free to overwrite

        if (k0 + 32 < kEnd) stage(k0 + 32);   // issue next staging; MFMAs hide it

#pragma unroll
        for (int m = 0; m < 4; ++m)
#pragma unroll
            for (int n = 0; n < 4; ++n) {
                acc[m][n] = __builtin_amdgcn_mfma_f32_16x16x32_bf16(ah[m], bh[n], acc[m][n], 0, 0, 0);
                acc[m][n] = __builtin_amdgcn_mfma_f32_16x16x32_bf16(ah[m], bl[n], acc[m][n], 0, 0, 0);
                acc[m][n] = __builtin_amdgcn_mfma_f32_16x16x32_bf16(al[m], bh[n], acc[m][n], 0, 0, 0);
            }
    }

    // epilogue: C/D layout col=lane&15, row=(lane>>4)*4+reg
#pragma unroll
    for (int m = 0; m < 4; ++m) {
        const int row = bm * 128 + wm * 64 + m * 16 + ((lane >> 4) << 2);
#pragma unroll
        for (int n = 0; n < 4; ++n) {
            const int col = bn * 128 + wn * 64 + n * 16 + (lane & 15);
#pragma unroll
            for (int r = 0; r < 4; ++r)
                Cp[(size_t)(row + r) * N + col] = acc[m][n][r];
        }
    }
}

// ---------------------------------------------------------------------------
// o = a + b (float4 granularity) — split-K reduction epilogue.
// ---------------------------------------------------------------------------
__global__ void add2_kernel(const float* __restrict__ a, const float* __restrict__ b,
                            float* __restrict__ o, int n4)
{
    int i = blockIdx.x * blockDim.x + threadIdx.x;
    if (i >= n4) return;
    float4 va = ((const float4*)a)[i];
    float4 vb = ((const float4*)b)[i];
    ((float4*)o)[i] = make_float4(va.x + vb.x, va.y + vb.y, va.z + vb.z, va.w + vb.w);
}

// ---------------------------------------------------------------------------
// Depthwise causal conv (k=4) + bias + SiLU (fast).
// ---------------------------------------------------------------------------
__global__ void conv_silu_kernel(const float* __restrict__ xz,
                                 const float* __restrict__ conv_w,
                                 const float* __restrict__ conv_b,
                                 float* __restrict__ xi)
{
    int idx = blockIdx.x * blockDim.x + threadIdx.x;
    if (idx >= NTOK * D_INNER) return;
    int d = idx % D_INNER;
    int t = idx / D_INNER;
    int l = t % SEQ;
    int b = t / SEQ;

    float w0 = conv_w[d * 4 + 0], w1 = conv_w[d * 4 + 1];
    float w2 = conv_w[d * 4 + 2], w3 = conv_w[d * 4 + 3];

    const float* base = xz + ((size_t)b * SEQ) * NXZ + d;
    float acc = conv_b[d];
    if (l >= 3) acc = fmaf(w0, base[(size_t)(l - 3) * NXZ], acc);
    if (l >= 2) acc = fmaf(w1, base[(size_t)(l - 2) * NXZ], acc);
    if (l >= 1) acc = fmaf(w2, base[(size_t)(l - 1) * NXZ], acc);
    acc = fmaf(w3, base[(size_t)l * NXZ], acc);
    xi[idx] = silu_fast(acc);
}

// ---------------------------------------------------------------------------
// x_dbl: XT tokens per block; one W_x read feeds XT FMA streams.
// Padded row layout: slot 0 = dt_raw, 4..19 = B, 20..35 = C.
// ---------------------------------------------------------------------------
__launch_bounds__(256)
__global__ void xdbl_kernel(const float* __restrict__ xi,
                            const float* __restrict__ W_x,
                            float* __restrict__ xdbl)
{
    __shared__ float rows[XT][D_INNER];
    const int t0 = blockIdx.x * XT;
    for (int i = threadIdx.x; i < XT * D_INNER; i += 256)
        rows[i >> 11][i & 2047] = xi[(size_t)(t0 + (i >> 11)) * D_INNER + (i & 2047)];
    __syncthreads();

    const int wave = threadIdx.x >> 6;
    const int lane = threadIdx.x & 63;
    for (int e = wave; e < NDBL; e += 4) {
        const float* wr = W_x + (size_t)e * D_INNER;
        float s0 = 0.f, s1 = 0.f, s2 = 0.f, s3 = 0.f;
        for (int i = lane; i < D_INNER; i += 64) {
            float w = wr[i];
            s0 = fmaf(rows[0][i], w, s0);
            s1 = fmaf(rows[1][i], w, s1);
            s2 = fmaf(rows[2][i], w, s2);
            s3 = fmaf(rows[3][i], w, s3);
        }
#pragma unroll
        for (int off = 32; off; off >>= 1) {
            s0 += __shfl_xor(s0, off);
            s1 += __shfl_xor(s1, off);
            s2 += __shfl_xor(s2, off);
            s3 += __shfl_xor(s3, off);
        }
        if (lane == 0) {
            const int slot = (e == 0 ? 0 : e + 3);
            xdbl[(size_t)(t0 + 0) * XROW + slot] = s0;
            xdbl[(size_t)(t0 + 1) * XROW + slot] = s1;
            xdbl[(size_t)(t0 + 2) * XROW + slot] = s2;
            xdbl[(size_t)(t0 + 3) * XROW + slot] = s3;
        }
    }
}

// ---------------------------------------------------------------------------
// Chunked scan pass 1: thread per (b, d, chunk); all 16 n-states in registers.
// ---------------------------------------------------------------------------
__launch_bounds__(256)
__global__ void scan_pass1(const float* __restrict__ xdbl,
                           const float* __restrict__ xi,
                           const float* __restrict__ W_dt,
                           const float* __restrict__ b_dt,
                           const float* __restrict__ A_log,
                           float* __restrict__ aprod,
                           float* __restrict__ hloc)
{
    const int d = blockIdx.x * 256 + threadIdx.x;
    const int c = blockIdx.y;
    const int b = blockIdx.z;

    float A[16];
    {
        const float4* ar = (const float4*)(A_log + (size_t)d * 16);
#pragma unroll
        for (int q = 0; q < 4; ++q) {
            float4 v = ar[q];
            A[q * 4 + 0] = -__expf(v.x);
            A[q * 4 + 1] = -__expf(v.y);
            A[q * 4 + 2] = -__expf(v.z);
            A[q * 4 + 3] = -__expf(v.w);
        }
    }
    const float wdt = W_dt[d], bdt = b_dt[d];

    const float* xd = xdbl + ((size_t)b * SEQ + c * CHUNK) * XROW;
    const float* xp = xi + ((size_t)b * SEQ + c * CHUNK) * D_INNER + d;

    float h[16], ap[16], Bv[16];
#pragma unroll
    for (int n = 0; n < 16; ++n) { h[n] = 0.f; ap[n] = 1.f; }

    for (int l = 0; l < CHUNK; ++l) {
        float raw = xd[0];
#pragma unroll
        for (int q = 0; q < 4; ++q) {
            float4 v = *(const float4*)(xd + 4 + q * 4);
            Bv[q * 4 + 0] = v.x; Bv[q * 4 + 1] = v.y;
            Bv[q * 4 + 2] = v.z; Bv[q * 4 + 3] = v.w;
        }
        float xv = xp[0];
        float dtv = softplus_fast(fmaf(raw, wdt, bdt));
        float dtx = dtv * xv;
#pragma unroll
        for (int n = 0; n < 16; ++n) {
            float e = __expf(dtv * A[n]);
            h[n]  = fmaf(e, h[n], Bv[n] * dtx);
            ap[n] *= e;
        }
        xd += XROW; xp += D_INNER;
    }

    size_t s = (((size_t)b * NCHUNK + c) * D_INNER + d) * 16;
#pragma unroll
    for (int q = 0; q < 4; ++q) {
        *(float4*)(aprod + s + q * 4) = make_float4(ap[q*4], ap[q*4+1], ap[q*4+2], ap[q*4+3]);
        *(float4*)(hloc  + s + q * 4) = make_float4(h[q*4],  h[q*4+1],  h[q*4+2],  h[q*4+3]);
    }
}

// ---------------------------------------------------------------------------
// Chunked scan combine: serial over NCHUNK summaries; h_start in-place.
// ---------------------------------------------------------------------------
__global__ void scan_combine(float* __restrict__ aprod,
                             const float* __restrict__ hloc)
{
    int idx = blockIdx.x * blockDim.x + threadIdx.x;  // b*32768 + d*16 + n
    int b  = idx >> 15;
    int dn = idx & 32767;
    float hs = 0.f;
#pragma unroll
    for (int c = 0; c < NCHUNK; ++c) {
        size_t s = (((size_t)b * NCHUNK + c) << 15) + dn;
        float ap = aprod[s];
        float hl = hloc[s];
        aprod[s] = hs;                 // h_start for this chunk
        hs = fmaf(ap, hs, hl);
    }
}

// ---------------------------------------------------------------------------
// Chunked scan pass 2: rescan from h_start; emit gated y in-place into xi.
// ---------------------------------------------------------------------------
__launch_bounds__(256)
__global__ void scan_pass2(const float* __restrict__ xdbl,
                           float* __restrict__ xi,
                           const float* __restrict__ xz,
                           const float* __restrict__ W_dt,
                           const float* __restrict__ b_dt,
                           const float* __restrict__ A_log,
                           const float* __restrict__ Dvec,
                           const float* __restrict__ hstart)
{
    const int d = blockIdx.x * 256 + threadIdx.x;
    const int c = blockIdx.y;
    const int b = blockIdx.z;

    float A[16];
    {
        const float4* ar = (const float4*)(A_log + (size_t)d * 16);
#pragma unroll
        for (int q = 0; q < 4; ++q) {
            float4 v = ar[q];
            A[q * 4 + 0] = -__expf(v.x);
            A[q * 4 + 1] = -__expf(v.y);
            A[q * 4 + 2] = -__expf(v.z);
            A[q * 4 + 3] = -__expf(v.w);
        }
    }
    const float wdt = W_dt[d], bdt = b_dt[d], Dd = Dvec[d];

    const float* xd = xdbl + ((size_t)b * SEQ + c * CHUNK) * XROW;
    float*       xp = xi + ((size_t)b * SEQ + c * CHUNK) * D_INNER + d;
    const float* zp = xz + ((size_t)b * SEQ + c * CHUNK) * NXZ + D_INNER + d;

    float h[16], Bv[16], Cv[16];
    {
        size_t s = (((size_t)b * NCHUNK + c) * D_INNER + d) * 16;
#pragma unroll
        for (int q = 0; q < 4; ++q) {
            float4 v = *(const float4*)(hstart + s + q * 4);
            h[q * 4 + 0] = v.x; h[q * 4 + 1] = v.y;
            h[q * 4 + 2] = v.z; h[q * 4 + 3] = v.w;
        }
    }

    for (int l = 0; l < CHUNK; ++l) {
        float raw = xd[0];
#pragma unroll
        for (int q = 0; q < 4; ++q) {
            float4 v = *(const float4*)(xd + 4 + q * 4);
            Bv[q * 4 + 0] = v.x; Bv[q * 4 + 1] = v.y;
            Bv[q * 4 + 2] = v.z; Bv[q * 4 + 3] = v.w;
            float4 w = *(const float4*)(xd + 20 + q * 4);
            Cv[q * 4 + 0] = w.x; Cv[q * 4 + 1] = w.y;
            Cv[q * 4 + 2] = w.z; Cv[q * 4 + 3] = w.w;
        }
        float xv = xp[0];
        float zv = zp[0];
        float dtv = softplus_fast(fmaf(raw, wdt, bdt));
        float dtx = dtv * xv;

        float p0 = 0.f, p1 = 0.f, p2 = 0.f, p3 = 0.f;
#pragma unroll
        for (int q = 0; q < 4; ++q) {
            float e0 = __expf(dtv * A[q*4+0]);
            float e1 = __expf(dtv * A[q*4+1]);
            float e2 = __expf(dtv * A[q*4+2]);
            float e3 = __expf(dtv * A[q*4+3]);
            h[q*4+0] = fmaf(e0, h[q*4+0], Bv[q*4+0] * dtx);
            h[q*4+1] = fmaf(e1, h[q*4+1], Bv[q*4+1] * dtx);
            h[q*4+2] = fmaf(e2, h[q*4+2], Bv[q*4+2] * dtx);
            h[q*4+3] = fmaf(e3, h[q*4+3], Bv[q*4+3] * dtx);
            p0 = fmaf(h[q*4+0], Cv[q*4+0], p0);
            p1 = fmaf(h[q*4+1], Cv[q*4+1], p1);
            p2 = fmaf(h[q*4+2], Cv[q*4+2], p2);
            p3 = fmaf(h[q*4+3], Cv[q*4+3], p3);
        }
        float y = (p0 + p1) + (p2 + p3) + Dd * xv;
        xp[0] = y * silu_fast(zv);

        xd += XROW; xp += D_INNER; zp += NXZ;
    }
}

// ---------------------------------------------------------------------------
extern "C" void kernel_launch(void* const* d_in, const int* in_sizes, int n_in,
                              void* d_out, int out_size, void* d_ws, size_t ws_size,
                              hipStream_t stream)
{
    (void)in_sizes; (void)n_in; (void)out_size; (void)ws_size;

    const float* x      = (const float*)d_in[0];
    const float* W_in   = (const float*)d_in[1];
    const float* conv_w = (const float*)d_in[2];
    const float* conv_b = (const float*)d_in[3];
    const float* W_x    = (const float*)d_in[4];
    const float* W_dt   = (const float*)d_in[5];
    const float* b_dt   = (const float*)d_in[6];
    const float* A_log  = (const float*)d_in[7];
    const float* Dvec   = (const float*)d_in[8];
    const float* W_out  = (const float*)d_in[9];
    float* out = (float*)d_out;

    // ---- workspace map ----
    float* xz   = (float*)d_ws;                    // 4096x4096 f32 (64MB)
    float* xi   = xz + (size_t)NTOK * NXZ;         // 4096x2048 f32 (33.5MB)
    float* xdbl = xi + (size_t)NTOK * D_INNER;     // 4096x40 f32 (padded)
    float* R    = xdbl + (size_t)NTOK * XROW;      // shared region

    // phase-1 occupants of R: hi/lo splits of x and W_in (33.5MB)
    short* x_hi   = (short*)R;
    short* x_lo   = x_hi + (size_t)NTOK * D_MODEL;
    short* Win_hi = x_lo + (size_t)NTOK * D_MODEL;
    short* Win_lo = Win_hi + (size_t)NXZ * D_MODEL;
    // phase-2 occupants of R: scan buffers (aprod doubles as hstart; 33.5MB)
    float* aprod  = R;
    float* hloc   = aprod + (size_t)BATCH * NCHUNK * D_INNER * 16;
    // phase-3 occupants of xz region (z consumed by pass2): y / W_out splits
    short* y_hi   = (short*)xz;
    short* y_lo   = y_hi + (size_t)NTOK * D_INNER;
    short* Wou_hi = y_lo + (size_t)NTOK * D_INNER;
    short* Wou_lo = Wou_hi + (size_t)D_MODEL * D_INNER;
    // phase-3 occupants of xi region (xi dead after y split): split-K partials
    float* part0  = xi;                            // 4096x1024
    float* part1  = part0 + (size_t)NTOK * D_MODEL;

    // 0) split x and W_in to bf16 hi/lo
    split_kernel<<<(NTOK * D_MODEL / 4 + 255) / 256, 256, 0, stream>>>(x, x_hi, x_lo, NTOK * D_MODEL / 4);
    split_kernel<<<(NXZ * D_MODEL / 4 + 255) / 256, 256, 0, stream>>>(W_in, Win_hi, Win_lo, NXZ * D_MODEL / 4);

    // 1) xz = x @ W_in^T   (M=4096, N=4096, K=1024; single K-slab)
    {
        dim3 grid(NXZ / 128, NTOK / 128, 1);   // 1024 blocks
        mfma_gemm_split<<<grid, 256, 0, stream>>>(x_hi, x_lo, Win_hi, Win_lo, xz,
                                                  NTOK, NXZ, D_MODEL, D_MODEL, 0);
    }
    // 2) depthwise conv + SiLU -> xi
    {
        int total = NTOK * D_INNER;
        conv_silu_kernel<<<(total + 255) / 256, 256, 0, stream>>>(xz, conv_w, conv_b, xi);
    }
    // 3) x_dbl = xi @ W_x^T  (padded rows)
    xdbl_kernel<<<NTOK / XT, 256, 0, stream>>>(xi, W_x, xdbl);

    // 4) chunked selective scan (register-resident n-states)
    {
        dim3 grid(D_INNER / 256, NCHUNK, BATCH);
        scan_pass1<<<grid, 256, 0, stream>>>(xdbl, xi, W_dt, b_dt, A_log, aprod, hloc);
        scan_combine<<<(BATCH * D_INNER * 16) / 256, 256, 0, stream>>>(aprod, hloc);
        scan_pass2<<<grid, 256, 0, stream>>>(xdbl, xi, xz, W_dt, b_dt, A_log, Dvec, aprod);
    }
    // 5) split y (=xi) and W_out; out = y @ W_out^T via split-K=2 + add
    split_kernel<<<(NTOK * D_INNER / 4 + 255) / 256, 256, 0, stream>>>(xi, y_hi, y_lo, NTOK * D_INNER / 4);
    split_kernel<<<(D_MODEL * D_INNER / 4 + 255) / 256, 256, 0, stream>>>(W_out, Wou_hi, Wou_lo, D_MODEL * D_INNER / 4);
    {
        dim3 grid(D_MODEL / 128, NTOK / 128, 2);   // 512 blocks (2 k-halves)
        mfma_gemm_split<<<grid, 256, 0, stream>>>(y_hi, y_lo, Wou_hi, Wou_lo, part0,
                                                  NTOK, D_MODEL, D_INNER, D_INNER / 2,
                                                  (size_t)NTOK * D_MODEL);
        add2_kernel<<<(NTOK * D_MODEL / 4 + 255) / 256, 256, 0, stream>>>(part0, part1, out, NTOK * D_MODEL / 4);
    }
}